// Round 15
// baseline (330.915 us; speedup 1.0000x reference)
//
#include <hip/hip_runtime.h>
#include <math.h>

// Problem constants (from reference)
#define NN 50000
#define NE 800000
#define NFEAT 128
#define NHID 64
#define NCLASS 16
#define NB_SCAN ((NN + 255) / 256)  // 196
#define GB ((NN + 63) / 64)         // 782 row-tiles for layer-1 GEMM
#define SGRP 4                      // scatter destination groups
#define ROWS_PER_SGRP ((NN + SGRP - 1) / SGRP)  // 12500
#define SCHUNKS 392                 // scatter chunks per group
#define EMAX 1024                   // LDS edge-stage capacity, 8-row blocks (mean 128)
#define EMAX4 512                   // LDS edge-stage capacity, 4-row blocks (mean 64)

// fp32 <-> bf16 helpers (RNE round)
__device__ inline unsigned short f2bf(float f) {
    unsigned u = __builtin_bit_cast(unsigned, f);
    u += 0x7fffu + ((u >> 16) & 1u);
    return (unsigned short)(u >> 16);
}
__device__ inline float bf2f(unsigned short h) {
    return __builtin_bit_cast(float, (unsigned)h << 16);
}
// Packed edge: low 16 = col (NN < 65536), high 16 = weight as bf16.
__device__ inline float pk_w(unsigned v) { return bf2f((unsigned short)(v >> 16)); }
__device__ inline int pk_c(unsigned v) { return (int)(v & 0xffffu); }

// ---------------- K1: hist + pack (rank via atomicAdd return) ----------------
__global__ __launch_bounds__(256) void hist_pack_kernel(const int* __restrict__ erow,
                                                        const int* __restrict__ ecol,
                                                        const float* __restrict__ ew,
                                                        int* __restrict__ deg,
                                                        uint2* __restrict__ rr8, int E) {
    int e = blockIdx.x * 256 + threadIdx.x;
    if (e < E) {
        int r = erow[e];
        int k = atomicAdd(&deg[r], 1);
        uint2 v;
        v.x = ((unsigned)r << 16) | (unsigned)k;
        v.y = ((unsigned)f2bf(ew[e]) << 16) | (unsigned)ecol[e];
        rr8[e] = v;
    }
}

// ---------------- K2: single-dispatch scan -> row_ptr (R14-validated) ----------------
// Block c computes its own prefix sum(deg[0..c*256)) directly (deg is 200KB,
// L2/L3-resident after hist), then Hillis-Steele scans its chunk.
__global__ __launch_bounds__(256) void scan_merged_kernel(const int* __restrict__ deg,
                                                          int* __restrict__ row_ptr, int n) {
    __shared__ int s[256];
    const int t = threadIdx.x;
    const int c = blockIdx.x;

    // phase A: blockpre = sum of deg[0 .. c*256)
    int part = 0;
    for (int i = t; i < c * 256; i += 256) part += deg[i];
    s[t] = part;
    __syncthreads();
#pragma unroll
    for (int off = 128; off > 0; off >>= 1) {
        if (t < off) s[t] += s[t + off];
        __syncthreads();
    }
    const int blockpre = s[0];
    __syncthreads();

    // phase B: intra-chunk inclusive scan
    int i = c * 256 + t;
    int d = (i < n) ? deg[i] : 0;
    s[t] = d;
    __syncthreads();
    for (int off = 1; off < 256; off <<= 1) {
        int u = (t >= off) ? s[t - off] : 0;
        __syncthreads();
        s[t] += u;
        __syncthreads();
    }
    int excl = blockpre + s[t] - d;
    if (i < n) {
        row_ptr[i] = excl;
        if (i == n - 1) row_ptr[n] = excl + d;
    }
}

// ---------------- K3: static partitioned rank-scatter (baseline-validated) ----------------
__global__ __launch_bounds__(256) void scatter_rank8_kernel(const uint2* __restrict__ rr8,
                                                            const int* __restrict__ row_ptr,
                                                            unsigned* __restrict__ pk, int E) {
    const int g = blockIdx.x & (SGRP - 1);
    const int chunk = blockIdx.x / SGRP;
    const int CH = (E + SCHUNKS - 1) / SCHUNKS;
    const int lo = chunk * CH;
    const int hi = (lo + CH < E) ? lo + CH : E;
    const int rlo = g * ROWS_PER_SGRP;
    const int rhi = (rlo + ROWS_PER_SGRP < NN) ? rlo + ROWS_PER_SGRP : NN;
    for (int e = lo + threadIdx.x; e < hi; e += 256) {
        uint2 v = rr8[e];
        int r = (int)(v.x >> 16);
        if (r >= rlo && r < rhi) {
            pk[row_ptr[r] + (int)(v.x & 0xffffu)] = v.y;
        }
    }
}

// ---------------- K4: Layer-1 GEMM: out[M,64] = in[M,128] @ W[128,64], bf16 out ----------------
// Original 64-row tile, W + x staged in LDS (the fast, baseline-validated form).
template <int K, bool RELU_IN>
__global__ __launch_bounds__(256) void gemm64_kernel(const float* __restrict__ in,
                                                     const float* __restrict__ Wg,
                                                     unsigned short* __restrict__ outb, int M) {
    constexpr int KC = 64;
    __shared__ float xs[KC][68];
    __shared__ float Ws[KC][64];
    const int t = threadIdx.x;
    const int tx = t % 16;
    const int ty = t / 16;
    const int r0 = blockIdx.x * 64;

    float acc[4][4];
#pragma unroll
    for (int i = 0; i < 4; i++)
#pragma unroll
        for (int j = 0; j < 4; j++) acc[i][j] = 0.f;

    for (int k0 = 0; k0 < K; k0 += KC) {
        for (int i = t * 4; i < KC * 64; i += 1024) {
            *(float4*)&Ws[i / 64][i % 64] = *(const float4*)&Wg[(size_t)k0 * 64 + i];
        }
        {
            const int r = t / 4;
            const int q = t % 4;
            const int gr = r0 + r;
#pragma unroll
            for (int i = 0; i < 4; i++) {
                int k = q * 16 + i * 4;
                float4 v;
                if (gr < M)
                    v = *(const float4*)&in[(size_t)gr * K + k0 + k];
                else
                    v = make_float4(0.f, 0.f, 0.f, 0.f);
                if (RELU_IN) {
                    v.x = fmaxf(v.x, 0.f);
                    v.y = fmaxf(v.y, 0.f);
                    v.z = fmaxf(v.z, 0.f);
                    v.w = fmaxf(v.w, 0.f);
                }
                xs[k + 0][r] = v.x;
                xs[k + 1][r] = v.y;
                xs[k + 2][r] = v.z;
                xs[k + 3][r] = v.w;
            }
        }
        __syncthreads();
#pragma unroll 8
        for (int k = 0; k < KC; k++) {
            float4 xv = *(const float4*)&xs[k][ty * 4];
            float4 wv = *(const float4*)&Ws[k][tx * 4];
            acc[0][0] += xv.x * wv.x; acc[0][1] += xv.x * wv.y;
            acc[0][2] += xv.x * wv.z; acc[0][3] += xv.x * wv.w;
            acc[1][0] += xv.y * wv.x; acc[1][1] += xv.y * wv.y;
            acc[1][2] += xv.y * wv.z; acc[1][3] += xv.y * wv.w;
            acc[2][0] += xv.z * wv.x; acc[2][1] += xv.z * wv.y;
            acc[2][2] += xv.z * wv.z; acc[2][3] += xv.z * wv.w;
            acc[3][0] += xv.w * wv.x; acc[3][1] += xv.w * wv.y;
            acc[3][2] += xv.w * wv.z; acc[3][3] += xv.w * wv.w;
        }
        __syncthreads();
    }
#pragma unroll
    for (int i = 0; i < 4; i++) {
        int r = r0 + ty * 4 + i;
        if (r < M) {
            ushort4 u;
            u.x = f2bf(acc[i][0]);
            u.y = f2bf(acc[i][1]);
            u.z = f2bf(acc[i][2]);
            u.w = f2bf(acc[i][3]);
            *(ushort4*)&outb[(size_t)r * 64 + tx * 4] = u;
        }
    }
}

// ---------------- Fused SpMM(F=64) + next-layer dense GEMM (R9-validated) ----------------
// Quarter-wave mapping: wave = 2 rows x 2 edge-slots x 16 feat-lanes(x4 feats).
// One gather instruction = 8 lines in flight; 8-gather batch = 64 lines/wave.
// Block's contiguous edge range staged into 4KB LDS. Epilogue reads W from L2.
template <int NOUT>
__global__ __launch_bounds__(256, 8) void spmm64_fused_kernel(
    const unsigned short* __restrict__ gb,   // gather source [*,64] bf16
    const int* __restrict__ row_ptr,
    const unsigned* __restrict__ pk,
    const float* __restrict__ bias,
    const float* __restrict__ Wn,            // [64, NOUT] fp32 (next layer)
    float* __restrict__ e_out,               // [M,64] fp32 (required output)
    unsigned short* __restrict__ nxt,        // [M,NOUT] bf16 (next layer input)
    int M) {
    __shared__ float xs[8][64];
    __shared__ unsigned epk[EMAX];
    const int t = threadIdx.x;
    const int lane = t & 63;
    const int rb = t >> 5;            // row-in-block 0..7 (half-wave)
    const int slot = (lane >> 4) & 1; // edge slot within row (quarter-wave)
    const int fl = (lane & 15) * 4;   // feature base: 4 feats per lane

    const int blk0 = blockIdx.x * 8;
    const int base = row_ptr[blk0];
    const int cnt = row_ptr[blk0 + 8] - base;
    const bool fits = (cnt <= EMAX);
    if (fits) {
        for (int i = t; i < cnt; i += 256) epk[i] = pk[base + i];
    }
    __syncthreads();

    const int r = blk0 + rb;
    float a0 = 0.f, a1 = 0.f, a2 = 0.f, a3 = 0.f;

#define FMA_EDGE(q, g)                                              \
    {                                                               \
        float w_ = pk_w(q);                                         \
        a0 += w_ * bf2f((unsigned short)((g).x & 0xffffu));         \
        a1 += w_ * bf2f((unsigned short)((g).x >> 16));             \
        a2 += w_ * bf2f((unsigned short)((g).y & 0xffffu));         \
        a3 += w_ * bf2f((unsigned short)((g).y >> 16));             \
    }
#define GLD(q) (*(const uint2*)&gb[(size_t)pk_c(q) * 64 + fl])

    if (fits) {
        int le = row_ptr[r] - base;
        const int lend = row_ptr[r + 1] - base;
        for (; le + 16 <= lend; le += 16) {
            unsigned q0 = epk[le + 0 + slot], q1 = epk[le + 2 + slot];
            unsigned q2 = epk[le + 4 + slot], q3 = epk[le + 6 + slot];
            unsigned q4 = epk[le + 8 + slot], q5 = epk[le + 10 + slot];
            unsigned q6 = epk[le + 12 + slot], q7 = epk[le + 14 + slot];
            uint2 g0 = GLD(q0), g1 = GLD(q1), g2 = GLD(q2), g3 = GLD(q3);
            uint2 g4 = GLD(q4), g5 = GLD(q5), g6 = GLD(q6), g7 = GLD(q7);
            FMA_EDGE(q0, g0); FMA_EDGE(q1, g1); FMA_EDGE(q2, g2); FMA_EDGE(q3, g3);
            FMA_EDGE(q4, g4); FMA_EDGE(q5, g5); FMA_EDGE(q6, g6); FMA_EDGE(q7, g7);
        }
        if (le + 8 <= lend) {
            unsigned q0 = epk[le + 0 + slot], q1 = epk[le + 2 + slot];
            unsigned q2 = epk[le + 4 + slot], q3 = epk[le + 6 + slot];
            uint2 g0 = GLD(q0), g1 = GLD(q1), g2 = GLD(q2), g3 = GLD(q3);
            FMA_EDGE(q0, g0); FMA_EDGE(q1, g1); FMA_EDGE(q2, g2); FMA_EDGE(q3, g3);
            le += 8;
        }
        if (le + 4 <= lend) {
            unsigned q0 = epk[le + 0 + slot], q1 = epk[le + 2 + slot];
            uint2 g0 = GLD(q0), g1 = GLD(q1);
            FMA_EDGE(q0, g0); FMA_EDGE(q1, g1);
            le += 4;
        }
        if (le + 2 <= lend) {
            unsigned q = epk[le + slot];
            uint2 g = GLD(q);
            FMA_EDGE(q, g);
            le += 2;
        }
        if (le < lend && slot == 0) {
            unsigned q = epk[le];
            uint2 g = GLD(q);
            FMA_EDGE(q, g);
        }
    } else {
        int e = row_ptr[r];
        const int end = row_ptr[r + 1];
        for (; e + 2 <= end; e += 2) {
            unsigned q = pk[e + slot];
            uint2 g = GLD(q);
            FMA_EDGE(q, g);
        }
        if (e < end && slot == 0) {
            unsigned q = pk[e];
            uint2 g = GLD(q);
            FMA_EDGE(q, g);
        }
    }
#undef GLD

    a0 += __shfl_xor(a0, 16);
    a1 += __shfl_xor(a1, 16);
    a2 += __shfl_xor(a2, 16);
    a3 += __shfl_xor(a3, 16);

    if (slot == 0) {
        float4 b4 = *(const float4*)&bias[fl];
        float4 v;
        v.x = a0 + b4.x;
        v.y = a1 + b4.y;
        v.z = a2 + b4.z;
        v.w = a3 + b4.w;
        *(float4*)&e_out[(size_t)r * 64 + fl] = v;
        xs[rb][fl + 0] = fmaxf(v.x, 0.f);
        xs[rb][fl + 1] = fmaxf(v.y, 0.f);
        xs[rb][fl + 2] = fmaxf(v.z, 0.f);
        xs[rb][fl + 3] = fmaxf(v.w, 0.f);
    }
    __syncthreads();

    // Epilogue GEMM: nxt[r][j] = sum_k relu(e[r][k]) * W[k][j]; W from L2.
    if (NOUT == 64) {
        const int rblk = t >> 6;
        const int j = t & 63;
        float acc0 = 0.f, acc1 = 0.f;
#pragma unroll 16
        for (int k = 0; k < 64; k++) {
            float w = Wn[k * 64 + j];
            acc0 += xs[rblk][k] * w;
            acc1 += xs[rblk + 4][k] * w;
        }
        nxt[(size_t)(blk0 + rblk) * 64 + j] = f2bf(acc0);
        nxt[(size_t)(blk0 + rblk + 4) * 64 + j] = f2bf(acc1);
    } else {
        if (t < 8 * NOUT) {
            const int rr = t / NOUT;
            const int j = t % NOUT;
            float acc = 0.f;
#pragma unroll 16
            for (int k = 0; k < 64; k++) acc += xs[rr][k] * Wn[k * NOUT + j];
            nxt[(size_t)(blk0 + rr) * NOUT + j] = f2bf(acc);
        }
    }
}

// ---------------- SpMM (F=16) fused with log_softmax, 16-slot gather (R10/R14-validated) ----------------
// Wave = 1 row x 16 edge-slots x 4 feat-lanes (uint2 = 4 of 16 feats).
// tmpc (1.6MB) is L2-resident. LDS edge staging, 4 rows/block.
__global__ __launch_bounds__(256, 8) void spmm16_lsm_kernel(const unsigned short* __restrict__ tmpc,
                                                            const int* __restrict__ row_ptr,
                                                            const unsigned* __restrict__ pk,
                                                            const float* __restrict__ bias,
                                                            float* __restrict__ e5,
                                                            float* __restrict__ out0, int M) {
    __shared__ unsigned epk[EMAX4];
    const int t = threadIdx.x;
    const int lane = t & 63;
    const int wv = t >> 6;          // row in block 0..3
    const int sl = lane >> 2;       // slot 0..15
    const int fq = (lane & 3) * 4;  // feature base

    const int blk0 = blockIdx.x * 4;
    const int base = row_ptr[blk0];
    const int cnt = row_ptr[blk0 + 4] - base;
    const bool fits = (cnt <= EMAX4);
    if (fits) {
        for (int i = t; i < cnt; i += 256) epk[i] = pk[base + i];
    }
    __syncthreads();

    const int r = blk0 + wv;
    float a0 = 0.f, a1 = 0.f, a2 = 0.f, a3 = 0.f;
#define FMA_EDGE(q, g)                                      \
    {                                                       \
        float w_ = pk_w(q);                                 \
        a0 += w_ * bf2f((unsigned short)((g).x & 0xffffu)); \
        a1 += w_ * bf2f((unsigned short)((g).x >> 16));     \
        a2 += w_ * bf2f((unsigned short)((g).y & 0xffffu)); \
        a3 += w_ * bf2f((unsigned short)((g).y >> 16));     \
    }
#define GLD16(q) (*(const uint2*)&tmpc[(size_t)pk_c(q) * 16 + fq])
    if (fits) {
        int le = row_ptr[r] - base;
        const int lend = row_ptr[r + 1] - base;
        for (; le + 16 <= lend; le += 16) {
            unsigned q = epk[le + sl];
            uint2 g = GLD16(q);
            FMA_EDGE(q, g);
        }
        int rem = lend - le;
        if (sl < rem) {
            unsigned q = epk[le + sl];
            uint2 g = GLD16(q);
            FMA_EDGE(q, g);
        }
    } else {
        int e = row_ptr[r];
        const int e1 = row_ptr[r + 1];
        for (; e + 16 <= e1; e += 16) {
            unsigned q = pk[e + sl];
            uint2 g = GLD16(q);
            FMA_EDGE(q, g);
        }
        int rem = e1 - e;
        if (sl < rem) {
            unsigned q = pk[e + sl];
            uint2 g = GLD16(q);
            FMA_EDGE(q, g);
        }
    }
#undef GLD16
#undef FMA_EDGE
    // reduce over slot bits (lane bits 2..5)
#pragma unroll
    for (int off = 4; off < 64; off <<= 1) {
        a0 += __shfl_xor(a0, off);
        a1 += __shfl_xor(a1, off);
        a2 += __shfl_xor(a2, off);
        a3 += __shfl_xor(a3, off);
    }
    float4 b4 = *(const float4*)&bias[fq];
    float v0 = a0 + b4.x, v1 = a1 + b4.y, v2 = a2 + b4.z, v3 = a3 + b4.w;

    float m = fmaxf(fmaxf(v0, v1), fmaxf(v2, v3));
    m = fmaxf(m, __shfl_xor(m, 1));
    m = fmaxf(m, __shfl_xor(m, 2));
    float s = expf(v0 - m) + expf(v1 - m) + expf(v2 - m) + expf(v3 - m);
    s += __shfl_xor(s, 1);
    s += __shfl_xor(s, 2);
    float ls = logf(s) + m;
    if (lane < 4) {
        float4 ev = make_float4(v0, v1, v2, v3);
        *(float4*)&e5[(size_t)r * 16 + fq] = ev;
        float4 ov = make_float4(v0 - ls, v1 - ls, v2 - ls, v3 - ls);
        *(float4*)&out0[(size_t)r * 16 + fq] = ov;
    }
}

// ---------------- launch ----------------

extern "C" void kernel_launch(void* const* d_in, const int* in_sizes, int n_in,
                              void* d_out, int out_size, void* d_ws, size_t ws_size,
                              hipStream_t stream) {
    const float* x = (const float*)d_in[0];
    const int* erow = (const int*)d_in[1];
    const int* ecol = (const int*)d_in[2];
    const float* ew = (const float*)d_in[3];
    const float* W1 = (const float*)d_in[4];
    const float* b1 = (const float*)d_in[5];
    const float* W2 = (const float*)d_in[6];
    const float* b2 = (const float*)d_in[7];
    const float* W3 = (const float*)d_in[8];
    const float* b3 = (const float*)d_in[9];
    const float* W4 = (const float*)d_in[10];
    const float* b4 = (const float*)d_in[11];
    const float* W5 = (const float*)d_in[12];
    const float* b5 = (const float*)d_in[13];

    // Output layout: log_softmax(e5), e1, e2, e3, e4, e5
    float* out0 = (float*)d_out;
    float* e1 = out0 + (size_t)NN * NCLASS;
    float* e2 = e1 + (size_t)NN * NHID;
    float* e3 = e2 + (size_t)NN * NHID;
    float* e4 = e3 + (size_t)NN * NHID;
    float* e5 = e4 + (size_t)NN * NHID;

    // Workspace layout
    char* ws = (char*)d_ws;
    unsigned short* tmpA = (unsigned short*)ws; ws += (size_t)NN * NHID * 2;   // 6.4 MB
    unsigned short* tmpB = (unsigned short*)ws; ws += (size_t)NN * NHID * 2;   // 6.4 MB
    unsigned short* tmpc = (unsigned short*)ws; ws += ((size_t)NN * NCLASS * 2 + 255) / 256 * 256;  // 1.6 MB
    int* deg = (int*)ws;      ws += ((size_t)NN * 4 + 255) / 256 * 256;        // zeroed below
    int* row_ptr = (int*)ws;  ws += ((size_t)(NN + 1) * 4 + 255) / 256 * 256;
    uint2* rr8 = (uint2*)ws;  ws += (size_t)NE * 8;                            // 6.4 MB packed records
    unsigned* pk = (unsigned*)ws; ws += (size_t)NE * 4;                        // 3.2 MB packed edges

    // ---- K0: zero deg ----
    hipMemsetAsync(deg, 0, (size_t)NN * 4, stream);

    // ---- K1: hist + pack ----
    hist_pack_kernel<<<(NE + 255) / 256, 256, 0, stream>>>(erow, ecol, ew, deg, rr8, NE);

    // ---- K2: single-dispatch scan -> row_ptr ----
    scan_merged_kernel<<<NB_SCAN, 256, 0, stream>>>(deg, row_ptr, NN);

    // ---- K3: static partitioned rank-scatter ----
    scatter_rank8_kernel<<<SGRP * SCHUNKS, 256, 0, stream>>>(rr8, row_ptr, pk, NE);

    // ---- K4: Layer 1 dense: tmpA = x @ W1 (bf16) ----
    gemm64_kernel<NFEAT, false><<<GB, 256, 0, stream>>>(x, W1, tmpA, NN);

    // ---- K5..K8: fused SpMM + next dense GEMM layers ----
    const int FG = NN / 8;  // 6250 blocks x 8 rows
    spmm64_fused_kernel<64><<<FG, 256, 0, stream>>>(tmpA, row_ptr, pk, b1, W2, e1, tmpB, NN);
    spmm64_fused_kernel<64><<<FG, 256, 0, stream>>>(tmpB, row_ptr, pk, b2, W3, e2, tmpA, NN);
    spmm64_fused_kernel<64><<<FG, 256, 0, stream>>>(tmpA, row_ptr, pk, b3, W4, e3, tmpB, NN);
    spmm64_fused_kernel<16><<<FG, 256, 0, stream>>>(tmpB, row_ptr, pk, b4, W5, e4, tmpc, NN);

    // ---- K9: SpMM(F=16) fused with log_softmax ----
    spmm16_lsm_kernel<<<(NN + 3) / 4, 256, 0, stream>>>(tmpc, row_ptr, pk, b5, e5, out0, NN);
}

// Round 17
// 305.781 us; speedup vs baseline: 1.0822x; 1.0822x over previous
//
#include <hip/hip_runtime.h>
#include <math.h>

// Problem constants (from reference)
#define NN 50000
#define NE 800000
#define NFEAT 128
#define NHID 64
#define NCLASS 16
#define NB_SCAN ((NN + 255) / 256)  // 196
#define GB ((NN + 63) / 64)         // 782 row-tiles for layer-1 GEMM
#define SGRP 4                      // scatter destination groups
#define ROWS_PER_SGRP ((NN + SGRP - 1) / SGRP)  // 12500
#define SCHUNKS 392                 // scatter chunks per group
#define EMAX 1024                   // LDS edge-stage capacity (mean/block = 128)

// fp32 <-> bf16 helpers (RNE round)
__device__ inline unsigned short f2bf(float f) {
    unsigned u = __builtin_bit_cast(unsigned, f);
    u += 0x7fffu + ((u >> 16) & 1u);
    return (unsigned short)(u >> 16);
}
__device__ inline float bf2f(unsigned short h) {
    return __builtin_bit_cast(float, (unsigned)h << 16);
}
// Packed edge: low 16 = col (NN < 65536), high 16 = weight as bf16.
__device__ inline float pk_w(unsigned v) { return bf2f((unsigned short)(v >> 16)); }
__device__ inline int pk_c(unsigned v) { return (int)(v & 0xffffu); }

// ---------------- CSR build ----------------

// Pack + rank: atomicAdd's return value IS the edge's rank within its row.
__global__ __launch_bounds__(256) void hist_pack_kernel(const int* __restrict__ erow,
                                                        const int* __restrict__ ecol,
                                                        const float* __restrict__ ew,
                                                        int* __restrict__ deg,
                                                        uint2* __restrict__ rr8, int E) {
    int e = blockIdx.x * 256 + threadIdx.x;
    if (e < E) {
        int r = erow[e];
        int k = atomicAdd(&deg[r], 1);
        uint2 v;
        v.x = ((unsigned)r << 16) | (unsigned)k;
        v.y = ((unsigned)f2bf(ew[e]) << 16) | (unsigned)ecol[e];
        rr8[e] = v;
    }
}

__global__ __launch_bounds__(256) void scan_sum_kernel(const int* __restrict__ deg,
                                                       int* __restrict__ blocksum, int n) {
    __shared__ int s[256];
    const int t = threadIdx.x;
    int i = blockIdx.x * 256 + t;
    s[t] = (i < n) ? deg[i] : 0;
    __syncthreads();
#pragma unroll
    for (int off = 128; off > 0; off >>= 1) {
        if (t < off) s[t] += s[t + off];
        __syncthreads();
    }
    if (t == 0) blocksum[blockIdx.x] = s[0];
}

__global__ __launch_bounds__(256) void scan_final_kernel(const int* __restrict__ deg,
                                                         const int* __restrict__ blocksum,
                                                         int* __restrict__ row_ptr, int n) {
    __shared__ int bs[256];
    __shared__ int s[256];
    const int t = threadIdx.x;
    bs[t] = (t < NB_SCAN) ? blocksum[t] : 0;
    __syncthreads();
    for (int off = 1; off < 256; off <<= 1) {
        int u = (t >= off) ? bs[t - off] : 0;
        __syncthreads();
        bs[t] += u;
        __syncthreads();
    }
    const int blockpre = (blockIdx.x == 0) ? 0 : bs[blockIdx.x - 1];

    int i = blockIdx.x * 256 + t;
    int d = (i < n) ? deg[i] : 0;
    s[t] = d;
    __syncthreads();
    for (int off = 1; off < 256; off <<= 1) {
        int u = (t >= off) ? s[t - off] : 0;
        __syncthreads();
        s[t] += u;
        __syncthreads();
    }
    int excl = blockpre + s[t] - d;
    if (i < n) {
        row_ptr[i] = excl;
        if (i == n - 1) row_ptr[n] = excl + d;
    }
}

// Static partitioned rank-scatter (baseline-validated).
__global__ __launch_bounds__(256) void scatter_rank8_kernel(const uint2* __restrict__ rr8,
                                                            const int* __restrict__ row_ptr,
                                                            unsigned* __restrict__ pk, int E) {
    const int g = blockIdx.x & (SGRP - 1);
    const int chunk = blockIdx.x / SGRP;
    const int CH = (E + SCHUNKS - 1) / SCHUNKS;
    const int lo = chunk * CH;
    const int hi = (lo + CH < E) ? lo + CH : E;
    const int rlo = g * ROWS_PER_SGRP;
    const int rhi = (rlo + ROWS_PER_SGRP < NN) ? rlo + ROWS_PER_SGRP : NN;
    for (int e = lo + threadIdx.x; e < hi; e += 256) {
        uint2 v = rr8[e];
        int r = (int)(v.x >> 16);
        if (r >= rlo && r < rhi) {
            pk[row_ptr[r] + (int)(v.x & 0xffffu)] = v.y;
        }
    }
}

// ---------------- Layer-1 GEMM: out[M,64] = in[M,128] @ W[128,64], bf16 out ----------------
template <int K, bool RELU_IN>
__global__ __launch_bounds__(256) void gemm64_kernel(const float* __restrict__ in,
                                                     const float* __restrict__ Wg,
                                                     unsigned short* __restrict__ outb, int M) {
    constexpr int KC = 64;
    __shared__ float xs[KC][68];
    __shared__ float Ws[KC][64];
    const int t = threadIdx.x;
    const int tx = t % 16;
    const int ty = t / 16;
    const int r0 = blockIdx.x * 64;

    float acc[4][4];
#pragma unroll
    for (int i = 0; i < 4; i++)
#pragma unroll
        for (int j = 0; j < 4; j++) acc[i][j] = 0.f;

    for (int k0 = 0; k0 < K; k0 += KC) {
        for (int i = t * 4; i < KC * 64; i += 1024) {
            *(float4*)&Ws[i / 64][i % 64] = *(const float4*)&Wg[(size_t)k0 * 64 + i];
        }
        {
            const int r = t / 4;
            const int q = t % 4;
            const int gr = r0 + r;
#pragma unroll
            for (int i = 0; i < 4; i++) {
                int k = q * 16 + i * 4;
                float4 v;
                if (gr < M)
                    v = *(const float4*)&in[(size_t)gr * K + k0 + k];
                else
                    v = make_float4(0.f, 0.f, 0.f, 0.f);
                if (RELU_IN) {
                    v.x = fmaxf(v.x, 0.f);
                    v.y = fmaxf(v.y, 0.f);
                    v.z = fmaxf(v.z, 0.f);
                    v.w = fmaxf(v.w, 0.f);
                }
                xs[k + 0][r] = v.x;
                xs[k + 1][r] = v.y;
                xs[k + 2][r] = v.z;
                xs[k + 3][r] = v.w;
            }
        }
        __syncthreads();
#pragma unroll 8
        for (int k = 0; k < KC; k++) {
            float4 xv = *(const float4*)&xs[k][ty * 4];
            float4 wv = *(const float4*)&Ws[k][tx * 4];
            acc[0][0] += xv.x * wv.x; acc[0][1] += xv.x * wv.y;
            acc[0][2] += xv.x * wv.z; acc[0][3] += xv.x * wv.w;
            acc[1][0] += xv.y * wv.x; acc[1][1] += xv.y * wv.y;
            acc[1][2] += xv.y * wv.z; acc[1][3] += xv.y * wv.w;
            acc[2][0] += xv.z * wv.x; acc[2][1] += xv.z * wv.y;
            acc[2][2] += xv.z * wv.z; acc[2][3] += xv.z * wv.w;
            acc[3][0] += xv.w * wv.x; acc[3][1] += xv.w * wv.y;
            acc[3][2] += xv.w * wv.z; acc[3][3] += xv.w * wv.w;
        }
        __syncthreads();
    }
#pragma unroll
    for (int i = 0; i < 4; i++) {
        int r = r0 + ty * 4 + i;
        if (r < M) {
            ushort4 u;
            u.x = f2bf(acc[i][0]);
            u.y = f2bf(acc[i][1]);
            u.z = f2bf(acc[i][2]);
            u.w = f2bf(acc[i][3]);
            *(ushort4*)&outb[(size_t)r * 64 + tx * 4] = u;
        }
    }
}

// ---------------- Fused SpMM(F=64) + next-layer dense GEMM, v3 (R9-validated) ----------------
// Quarter-wave mapping: wave = 2 rows x 2 edge-slots x 16 feat-lanes(x4 feats).
// One gather instruction = 2 rows x 2 edges x 2 cache lines = 8 lines in flight;
// an 8-gather batch = 64 lines/wave. Block's contiguous edge range staged into
// 4KB LDS (coalesced). Epilogue reads W directly from L2 -> LDS 6KB, 8 blk/CU.
template <int NOUT>
__global__ __launch_bounds__(256, 8) void spmm64_fused_kernel(
    const unsigned short* __restrict__ gb,   // gather source [*,64] bf16
    const int* __restrict__ row_ptr,
    const unsigned* __restrict__ pk,
    const float* __restrict__ bias,
    const float* __restrict__ Wn,            // [64, NOUT] fp32 (next layer)
    float* __restrict__ e_out,               // [M,64] fp32 (required output)
    unsigned short* __restrict__ nxt,        // [M,NOUT] bf16 (next layer input)
    int M) {
    __shared__ float xs[8][64];
    __shared__ unsigned epk[EMAX];
    const int t = threadIdx.x;
    const int lane = t & 63;
    const int rb = t >> 5;            // row-in-block 0..7 (half-wave)
    const int slot = (lane >> 4) & 1; // edge slot within row (quarter-wave)
    const int fl = (lane & 15) * 4;   // feature base: 4 feats per lane

    const int blk0 = blockIdx.x * 8;
    const int base = row_ptr[blk0];
    const int cnt = row_ptr[blk0 + 8] - base;
    const bool fits = (cnt <= EMAX);
    if (fits) {
        for (int i = t; i < cnt; i += 256) epk[i] = pk[base + i];
    }
    __syncthreads();

    const int r = blk0 + rb;
    float a0 = 0.f, a1 = 0.f, a2 = 0.f, a3 = 0.f;

#define FMA_EDGE(q, g)                                              \
    {                                                               \
        float w_ = pk_w(q);                                         \
        a0 += w_ * bf2f((unsigned short)((g).x & 0xffffu));         \
        a1 += w_ * bf2f((unsigned short)((g).x >> 16));             \
        a2 += w_ * bf2f((unsigned short)((g).y & 0xffffu));         \
        a3 += w_ * bf2f((unsigned short)((g).y >> 16));             \
    }
#define GLD(q) (*(const uint2*)&gb[(size_t)pk_c(q) * 64 + fl])

    if (fits) {
        int le = row_ptr[r] - base;
        const int lend = row_ptr[r + 1] - base;
        // 16-edge batches: 8 gathers/lane (2 slots x 8) -> 64 lines/wave in flight
        for (; le + 16 <= lend; le += 16) {
            unsigned q0 = epk[le + 0 + slot], q1 = epk[le + 2 + slot];
            unsigned q2 = epk[le + 4 + slot], q3 = epk[le + 6 + slot];
            unsigned q4 = epk[le + 8 + slot], q5 = epk[le + 10 + slot];
            unsigned q6 = epk[le + 12 + slot], q7 = epk[le + 14 + slot];
            uint2 g0 = GLD(q0), g1 = GLD(q1), g2 = GLD(q2), g3 = GLD(q3);
            uint2 g4 = GLD(q4), g5 = GLD(q5), g6 = GLD(q6), g7 = GLD(q7);
            FMA_EDGE(q0, g0); FMA_EDGE(q1, g1); FMA_EDGE(q2, g2); FMA_EDGE(q3, g3);
            FMA_EDGE(q4, g4); FMA_EDGE(q5, g5); FMA_EDGE(q6, g6); FMA_EDGE(q7, g7);
        }
        // straight-line tail ladder: 8, 4, 2, 1
        if (le + 8 <= lend) {
            unsigned q0 = epk[le + 0 + slot], q1 = epk[le + 2 + slot];
            unsigned q2 = epk[le + 4 + slot], q3 = epk[le + 6 + slot];
            uint2 g0 = GLD(q0), g1 = GLD(q1), g2 = GLD(q2), g3 = GLD(q3);
            FMA_EDGE(q0, g0); FMA_EDGE(q1, g1); FMA_EDGE(q2, g2); FMA_EDGE(q3, g3);
            le += 8;
        }
        if (le + 4 <= lend) {
            unsigned q0 = epk[le + 0 + slot], q1 = epk[le + 2 + slot];
            uint2 g0 = GLD(q0), g1 = GLD(q1);
            FMA_EDGE(q0, g0); FMA_EDGE(q1, g1);
            le += 4;
        }
        if (le + 2 <= lend) {
            unsigned q = epk[le + slot];
            uint2 g = GLD(q);
            FMA_EDGE(q, g);
            le += 2;
        }
        if (le < lend && slot == 0) {  // final odd edge: slot 0 only
            unsigned q = epk[le];
            uint2 g = GLD(q);
            FMA_EDGE(q, g);
        }
    } else {
        // fallback (effectively never taken; correctness only)
        int e = row_ptr[r];
        const int end = row_ptr[r + 1];
        for (; e + 2 <= end; e += 2) {
            unsigned q = pk[e + slot];
            uint2 g = GLD(q);
            FMA_EDGE(q, g);
        }
        if (e < end && slot == 0) {
            unsigned q = pk[e];
            uint2 g = GLD(q);
            FMA_EDGE(q, g);
        }
    }
#undef FMA_EDGE
#undef GLD

    // combine the two edge slots (lane x and x^16 hold same feats of same row)
    a0 += __shfl_xor(a0, 16);
    a1 += __shfl_xor(a1, 16);
    a2 += __shfl_xor(a2, 16);
    a3 += __shfl_xor(a3, 16);

    if (slot == 0) {
        float4 b4 = *(const float4*)&bias[fl];
        float4 v;
        v.x = a0 + b4.x;
        v.y = a1 + b4.y;
        v.z = a2 + b4.z;
        v.w = a3 + b4.w;
        *(float4*)&e_out[(size_t)r * 64 + fl] = v;
        xs[rb][fl + 0] = fmaxf(v.x, 0.f);
        xs[rb][fl + 1] = fmaxf(v.y, 0.f);
        xs[rb][fl + 2] = fmaxf(v.z, 0.f);
        xs[rb][fl + 3] = fmaxf(v.w, 0.f);
    }
    __syncthreads();

    // Epilogue GEMM: nxt[r][j] = sum_k relu(e[r][k]) * W[k][j]; W from L2 (coalesced per k)
    if (NOUT == 64) {
        const int rblk = t >> 6;  // wave-uniform -> xs reads broadcast (free)
        const int j = t & 63;
        float acc0 = 0.f, acc1 = 0.f;
#pragma unroll 16
        for (int k = 0; k < 64; k++) {
            float w = Wn[k * 64 + j];
            acc0 += xs[rblk][k] * w;
            acc1 += xs[rblk + 4][k] * w;
        }
        nxt[(size_t)(blk0 + rblk) * 64 + j] = f2bf(acc0);
        nxt[(size_t)(blk0 + rblk + 4) * 64 + j] = f2bf(acc1);
    } else {
        if (t < 8 * NOUT) {
            const int rr = t / NOUT;
            const int j = t % NOUT;
            float acc = 0.f;
#pragma unroll 16
            for (int k = 0; k < 64; k++) acc += xs[rr][k] * Wn[k * NOUT + j];
            nxt[(size_t)(blk0 + rr) * NOUT + j] = f2bf(acc);
        }
    }
}

// ---------------- SpMM (F=16) fused with log_softmax (R9-validated) ----------------
// One row per wave64: lane = 16*slot + f, 4 edge slots in parallel, shfl-reduce.
__global__ __launch_bounds__(256) void spmm16_lsm_kernel(const unsigned short* __restrict__ tmpc,
                                                         const int* __restrict__ row_ptr,
                                                         const unsigned* __restrict__ pk,
                                                         const float* __restrict__ bias,
                                                         float* __restrict__ e5,
                                                         float* __restrict__ out0, int M) {
    const int t = threadIdx.x;
    const int wv = __builtin_amdgcn_readfirstlane(t >> 6);  // wave 0..3
    const int lane = t & 63;
    const int f = lane & 15;
    const int s = lane >> 4;  // slot 0..3
    const int r = blockIdx.x * 4 + wv;
    if (r >= M) return;

    int e = row_ptr[r];
    const int end = row_ptr[r + 1];
    float acc = 0.f;
    for (; e + 8 <= end; e += 8) {
        unsigned qa = pk[e + s];
        unsigned qb = pk[e + 4 + s];
        acc += pk_w(qa) * bf2f(tmpc[(size_t)pk_c(qa) * 16 + f]);
        acc += pk_w(qb) * bf2f(tmpc[(size_t)pk_c(qb) * 16 + f]);
    }
    if (e + 4 <= end) {
        unsigned q = pk[e + s];
        acc += pk_w(q) * bf2f(tmpc[(size_t)pk_c(q) * 16 + f]);
        e += 4;
    }
    if (s < end - e) {
        unsigned q = pk[e + s];
        acc += pk_w(q) * bf2f(tmpc[(size_t)pk_c(q) * 16 + f]);
    }
    acc += __shfl_xor(acc, 16);
    acc += __shfl_xor(acc, 32);
    float v = acc + bias[f];

    float m = v;
#pragma unroll
    for (int off = 1; off < 16; off <<= 1) m = fmaxf(m, __shfl_xor(m, off, 16));
    float sum = expf(v - m);
#pragma unroll
    for (int off = 1; off < 16; off <<= 1) sum += __shfl_xor(sum, off, 16);
    float ls = logf(sum);
    if (lane < 16) {
        e5[(size_t)r * 16 + f] = v;
        out0[(size_t)r * 16 + f] = v - m - ls;
    }
}

// ---------------- launch ----------------

extern "C" void kernel_launch(void* const* d_in, const int* in_sizes, int n_in,
                              void* d_out, int out_size, void* d_ws, size_t ws_size,
                              hipStream_t stream) {
    const float* x = (const float*)d_in[0];
    const int* erow = (const int*)d_in[1];
    const int* ecol = (const int*)d_in[2];
    const float* ew = (const float*)d_in[3];
    const float* W1 = (const float*)d_in[4];
    const float* b1 = (const float*)d_in[5];
    const float* W2 = (const float*)d_in[6];
    const float* b2 = (const float*)d_in[7];
    const float* W3 = (const float*)d_in[8];
    const float* b3 = (const float*)d_in[9];
    const float* W4 = (const float*)d_in[10];
    const float* b4 = (const float*)d_in[11];
    const float* W5 = (const float*)d_in[12];
    const float* b5 = (const float*)d_in[13];

    // Output layout: log_softmax(e5), e1, e2, e3, e4, e5
    float* out0 = (float*)d_out;
    float* e1 = out0 + (size_t)NN * NCLASS;
    float* e2 = e1 + (size_t)NN * NHID;
    float* e3 = e2 + (size_t)NN * NHID;
    float* e4 = e3 + (size_t)NN * NHID;
    float* e5 = e4 + (size_t)NN * NHID;

    // Workspace layout
    char* ws = (char*)d_ws;
    unsigned short* tmpA = (unsigned short*)ws; ws += (size_t)NN * NHID * 2;   // 6.4 MB
    unsigned short* tmpB = (unsigned short*)ws; ws += (size_t)NN * NHID * 2;   // 6.4 MB
    unsigned short* tmpc = (unsigned short*)ws; ws += ((size_t)NN * NCLASS * 2 + 255) / 256 * 256;  // 1.6 MB
    int* deg = (int*)ws;      ws += ((size_t)NN * 4 + 255) / 256 * 256;        // zeroed below
    int* row_ptr = (int*)ws;  ws += ((size_t)(NN + 1) * 4 + 255) / 256 * 256;
    int* blocksum = (int*)ws; ws += ((size_t)NB_SCAN * 4 + 255) / 256 * 256;
    uint2* rr8 = (uint2*)ws;  ws += (size_t)NE * 8;                            // 6.4 MB packed records
    unsigned* pk = (unsigned*)ws; ws += (size_t)NE * 4;                        // 3.2 MB packed edges

    // ---- CSR build: pack+rank, scans, static partitioned rank-scatter ----
    hipMemsetAsync(deg, 0, (size_t)NN * 4, stream);
    hist_pack_kernel<<<(NE + 255) / 256, 256, 0, stream>>>(erow, ecol, ew, deg, rr8, NE);
    scan_sum_kernel<<<NB_SCAN, 256, 0, stream>>>(deg, blocksum, NN);
    scan_final_kernel<<<NB_SCAN, 256, 0, stream>>>(deg, blocksum, row_ptr, NN);
    scatter_rank8_kernel<<<SGRP * SCHUNKS, 256, 0, stream>>>(rr8, row_ptr, pk, NE);

    // ---- Layer 1 dense: tmpA = x @ W1 (bf16) ----
    gemm64_kernel<NFEAT, false><<<GB, 256, 0, stream>>>(x, W1, tmpA, NN);

    // ---- Layers 1-4: fused SpMM + next dense GEMM ----
    const int FG = NN / 8;  // 6250 blocks x 8 rows
    spmm64_fused_kernel<64><<<FG, 256, 0, stream>>>(tmpA, row_ptr, pk, b1, W2, e1, tmpB, NN);
    spmm64_fused_kernel<64><<<FG, 256, 0, stream>>>(tmpB, row_ptr, pk, b2, W3, e2, tmpA, NN);
    spmm64_fused_kernel<64><<<FG, 256, 0, stream>>>(tmpA, row_ptr, pk, b3, W4, e3, tmpB, NN);
    spmm64_fused_kernel<16><<<FG, 256, 0, stream>>>(tmpB, row_ptr, pk, b4, W5, e4, tmpc, NN);

    // ---- Layer 5: SpMM(F=16) fused with log_softmax ----
    spmm16_lsm_kernel<<<(NN + 3) / 4, 256, 0, stream>>>(tmpc, row_ptr, pk, b5, e5, out0, NN);
}